// Round 1
// baseline (422.511 us; speedup 1.0000x reference)
//
#include <hip/hip_runtime.h>
#include <cstdint>
#include <cstddef>

// Pipeline v5. B=4, T=2048, D=1024, H=16, HD=64. Inputs fp32, output fp32.
// attn v4: NO K/V LDS staging. V stored pre-transposed [bh][d][t] by the QKV
// epilogue; K and V^T MFMA fragments are loaded directly from global (16B/lane,
// L1/L2-resident: 8KB tiles reused by 4 waves). Only LDS use is the per-wave
// P strip (8KB/block) -> zero __syncthreads in attn, 4 blocks/CU resident.
// XCD-clustered block remap: XCD c owns heads 8c..8c+7 (per-XCD K+V ~= 4MB L2).
// GEMMs unchanged from v4 (m97-style global_load_lds width-16 staging).

typedef __bf16 bf16;
typedef __bf16 bf16x4 __attribute__((ext_vector_type(4)));
typedef __bf16 bf16x8 __attribute__((ext_vector_type(8)));
typedef float  f32x4  __attribute__((ext_vector_type(4)));
typedef float  fvec4  __attribute__((ext_vector_type(4)));
typedef unsigned u32x4 __attribute__((ext_vector_type(4)));

typedef __attribute__((address_space(1))) const void global_cv;
typedef __attribute__((address_space(3))) void lds_v;

#define MFMA16(a, b, c) __builtin_amdgcn_mfma_f32_16x16x32_bf16((a), (b), (c), 0, 0, 0)

// Q scale: 1/sqrt(64) * log2(e)  (softmax done in exp2 domain)
#define QSCALE 0.18033688f

__device__ __forceinline__ void async_ld16(const bf16* g, bf16* l) {
  // gfx950 16B direct global->LDS; dest = wave-uniform base + lane*16.
  __builtin_amdgcn_global_load_lds((global_cv*)g, (lds_v*)l, 16, 0, 0);
}

// XOR chunk swizzle for [rows][64] bf16 LDS tiles.
__device__ __forceinline__ int swz_off(int row, int col) {
  int sr = (row & 7) ^ ((row >> 3) & 7);
  return row * 64 + ((((col >> 3) ^ sr) & 7) * 8) + (col & 7);
}

__device__ __forceinline__ bf16x8 cvt8(const float* p) {
  fvec4 u = *(const fvec4*)p;
  fvec4 v = *(const fvec4*)(p + 4);
  bf16x8 r;
  r[0] = (bf16)u[0]; r[1] = (bf16)u[1]; r[2] = (bf16)u[2]; r[3] = (bf16)u[3];
  r[4] = (bf16)v[0]; r[5] = (bf16)v[1]; r[6] = (bf16)v[2]; r[7] = (bf16)v[3];
  return r;
}

// ---------------------------------------------------------------------------
// fp32 -> bf16 bulk convert (8 elems/thread).
// ---------------------------------------------------------------------------
__global__ void cvt_f32_bf16(const float* __restrict__ s, bf16* __restrict__ d,
                             int n8) {
  int i = blockIdx.x * 256 + threadIdx.x;
  if (i < n8) *(bf16x8*)(d + (size_t)i * 8) = cvt8(s + (size_t)i * 8);
}

// ---------------------------------------------------------------------------
// Shared epilogue: Q,K as [bh][t][64]; V TRANSPOSED as [bh][d][t].
// ---------------------------------------------------------------------------
__device__ __forceinline__ void qkv_scatter(const f32x4 acc[4][4], int m0, int n0,
                                            int wm, int wn, int quad, int l15,
                                            bf16* Qo, bf16* Ko, bf16* Vo) {
  const int which = n0 >> 10;  // 0=Q 1=K 2=V
  if (which == 2) {
    // V^T: [bh][d][t]; 4 accumulator rows per lane are t-consecutive -> 8B store
#pragma unroll
    for (int i = 0; i < 4; ++i) {
      const int m = m0 + wm + i * 16 + quad * 4;  // multiple of 4, no b-crossing
      const int b = m >> 11;
      const int t = m & 2047;
#pragma unroll
      for (int j = 0; j < 4; ++j) {
        const int n1 = (n0 + wn + j * 16 + l15) & 1023;
        const int h  = n1 >> 6;
        const int d  = n1 & 63;
        bf16x4 v;
#pragma unroll
        for (int r = 0; r < 4; ++r) v[r] = (bf16)acc[i][j][r];
        *(bf16x4*)(Vo + ((size_t)(b * 16 + h) * 64 + d) * 2048 + t) = v;
      }
    }
    return;
  }
  bf16* dst = (which == 0) ? Qo : Ko;
  const float scale = (which == 0) ? QSCALE : 1.0f;
#pragma unroll
  for (int i = 0; i < 4; ++i) {
    const int m = m0 + wm + i * 16 + quad * 4;
#pragma unroll
    for (int j = 0; j < 4; ++j) {
      const int n  = n0 + wn + j * 16 + l15;
      const int n1 = n & 1023;
      const int h  = n1 >> 6;
      const int d  = n1 & 63;
#pragma unroll
      for (int r = 0; r < 4; ++r) {
        const int mm = m + r;
        const int b  = mm >> 11;
        const int t  = mm & 2047;
        dst[(((size_t)(b * 16 + h)) * 2048 + t) * 64 + d] =
            (bf16)(acc[i][j][r] * scale);
      }
    }
  }
}

// ---------------------------------------------------------------------------
// QKV GEMM, bf16 async-staging variant (plan A). grid (24,64).
// ---------------------------------------------------------------------------
__global__ __launch_bounds__(256, 2)
void gemm_qkv_a(const bf16* __restrict__ A, const bf16* __restrict__ B,
                bf16* __restrict__ Qo, bf16* __restrict__ Ko,
                bf16* __restrict__ Vo) {
  __shared__ __align__(16) bf16 As[128 * 32];
  __shared__ __align__(16) bf16 Bs[128 * 32];
  const int K = 1024;

  const int tid  = threadIdx.x;
  const int lane = tid & 63;
  const int wave = tid >> 6;
  const int quad = lane >> 4;
  const int l15  = lane & 15;
  const int wm   = (wave >> 1) * 64;
  const int wn   = (wave & 1) * 64;
  const int m0   = blockIdx.y * 128;
  const int n0   = blockIdx.x * 128;

  f32x4 acc[4][4];
#pragma unroll
  for (int i = 0; i < 4; ++i)
#pragma unroll
    for (int j = 0; j < 4; ++j) acc[i][j] = f32x4{0.f, 0.f, 0.f, 0.f};

  const int r0 = tid >> 2;
  const int c0 = (tid & 3) * 8;
  const bf16* ag0 = A + (size_t)(m0 + r0) * K + c0;
  const bf16* ag1 = A + (size_t)(m0 + 64 + r0) * K + c0;
  const bf16* bg0 = B + (size_t)(n0 + r0) * K + c0;
  const bf16* bg1 = B + (size_t)(n0 + 64 + r0) * K + c0;
  const int lo0 = (wave * 64) * 8;        // wave-uniform LDS elem offset
  const int lo1 = (256 + wave * 64) * 8;

  for (int k0 = 0; k0 < K; k0 += 32) {
    __syncthreads();
    async_ld16(ag0 + k0, As + lo0);
    async_ld16(ag1 + k0, As + lo1);
    async_ld16(bg0 + k0, Bs + lo0);
    async_ld16(bg1 + k0, Bs + lo1);
    __syncthreads();

    bf16x8 af[4], bfr[4];
#pragma unroll
    for (int i = 0; i < 4; ++i)
      af[i] = *(const bf16x8*)(As + (wm + i * 16 + l15) * 32 + quad * 8);
#pragma unroll
    for (int j = 0; j < 4; ++j)
      bfr[j] = *(const bf16x8*)(Bs + (wn + j * 16 + l15) * 32 + quad * 8);
#pragma unroll
    for (int i = 0; i < 4; ++i)
#pragma unroll
      for (int j = 0; j < 4; ++j)
        acc[i][j] = MFMA16(af[i], bfr[j], acc[i][j]);
  }
  qkv_scatter(acc, m0, n0, wm, wn, quad, l15, Qo, Ko, Vo);
}

// ---------------------------------------------------------------------------
// QKV GEMM, fp32 cvt8 register-staging variant (plan B fallback). grid (24,64).
// ---------------------------------------------------------------------------
__global__ __launch_bounds__(256, 2)
void gemm_qkv_f(const float* __restrict__ A, const float* __restrict__ B,
                bf16* __restrict__ Qo, bf16* __restrict__ Ko,
                bf16* __restrict__ Vo) {
  __shared__ __align__(16) bf16 As[128 * 32];
  __shared__ __align__(16) bf16 Bs[128 * 32];
  const int K = 1024;

  const int tid  = threadIdx.x;
  const int lane = tid & 63;
  const int wave = tid >> 6;
  const int quad = lane >> 4;
  const int l15  = lane & 15;
  const int wm   = (wave >> 1) * 64;
  const int wn   = (wave & 1) * 64;
  const int m0   = blockIdx.y * 128;
  const int n0   = blockIdx.x * 128;

  f32x4 acc[4][4];
#pragma unroll
  for (int i = 0; i < 4; ++i)
#pragma unroll
    for (int j = 0; j < 4; ++j) acc[i][j] = f32x4{0.f, 0.f, 0.f, 0.f};

  const int r0 = tid >> 2;
  const int c0 = (tid & 3) * 8;
  const size_t aoff0 = (size_t)(m0 + r0) * K + c0;
  const size_t aoff1 = (size_t)(m0 + 64 + r0) * K + c0;
  const size_t boff0 = (size_t)(n0 + r0) * K + c0;
  const size_t boff1 = (size_t)(n0 + 64 + r0) * K + c0;

  for (int k0 = 0; k0 < K; k0 += 32) {
    bf16x8 va0 = cvt8(A + aoff0 + k0);
    bf16x8 va1 = cvt8(A + aoff1 + k0);
    bf16x8 vb0 = cvt8(B + boff0 + k0);
    bf16x8 vb1 = cvt8(B + boff1 + k0);
    __syncthreads();
    *(bf16x8*)(As + tid * 8)        = va0;
    *(bf16x8*)(As + 2048 + tid * 8) = va1;
    *(bf16x8*)(Bs + tid * 8)        = vb0;
    *(bf16x8*)(Bs + 2048 + tid * 8) = vb1;
    __syncthreads();

    bf16x8 af[4], bfr[4];
#pragma unroll
    for (int i = 0; i < 4; ++i)
      af[i] = *(const bf16x8*)(As + (wm + i * 16 + l15) * 32 + quad * 8);
#pragma unroll
    for (int j = 0; j < 4; ++j)
      bfr[j] = *(const bf16x8*)(Bs + (wn + j * 16 + l15) * 32 + quad * 8);
#pragma unroll
    for (int i = 0; i < 4; ++i)
#pragma unroll
      for (int j = 0; j < 4; ++j)
        acc[i][j] = MFMA16(af[i], bfr[j], acc[i][j]);
  }
  qkv_scatter(acc, m0, n0, wm, wn, quad, l15, Qo, Ko, Vo);
}

// ---------------------------------------------------------------------------
// Flash attention v4, causal. grid (16,64) remapped so XCD c (= lin%8) owns
// heads 8c..8c+7; block handles q-tiles {p, 31-p} (balanced: 33 kv-tiles).
// K fragments and V^T fragments loaded DIRECTLY from global (16B/lane; tiles
// are 8KB and reused by all 4 waves -> L1/L2 hits). Only LDS: per-wave P strip
// (swizzled). No __syncthreads anywhere; waves fully independent.
// No-max softmax in exp2 domain (log2e folded into Q scale); per-lane l
// accumulated across tiles, single 16-lane reduce at the end.
// ---------------------------------------------------------------------------
__global__ __launch_bounds__(256, 4)
void attn(const bf16* __restrict__ Q, const bf16* __restrict__ Kk,
          const bf16* __restrict__ Vt, bf16* __restrict__ Y) {
  __shared__ __align__(16) bf16 Ps[4 * 16 * 64];   // per-wave P strips, 8KB

  const int tid  = threadIdx.x;
  const int wave = tid >> 6;
  const int lane = tid & 63;
  const int quad = lane >> 4;
  const int l15  = lane & 15;

  // XCD-clustered remap: lin%8 = XCD; each XCD gets heads [8c, 8c+8).
  const int lin  = (int)blockIdx.x + ((int)blockIdx.y << 4);
  const int slot = lin >> 3;                 // 0..127 within XCD
  const int bh   = (lin & 7) * 8 + (slot >> 4);
  const int p    = slot & 15;
  const int b    = bh >> 4;
  const int h    = bh & 15;

  const bf16* Qb = Q  + (size_t)bh * (2048 * 64);
  const bf16* Kb = Kk + (size_t)bh * (2048 * 64);   // [t][64]
  const bf16* Vb = Vt + (size_t)bh * (2048 * 64);   // [64][2048] (transposed)
  bf16* Pw = Ps + wave * (16 * 64);

  // per-lane fragment base pointers
  const bf16* kl = Kb + (size_t)l15 * 64 + quad * 8;     // + (k0+j*16)*64 (+32)
  const bf16* vl = Vb + (size_t)l15 * 2048 + quad * 8;   // + j*16*2048 + k0 (+32)

  const float NEG = -1e30f;

#pragma unroll 1
  for (int pass = 0; pass < 2; ++pass) {
    const int qt = pass ? (31 - p) : p;
    const int q0 = qt * 64;

    const bf16* qp = Qb + (size_t)(q0 + wave * 16 + l15) * 64 + quad * 8;
    bf16x8 qa0 = *(const bf16x8*)qp;
    bf16x8 qa1 = *(const bf16x8*)(qp + 32);

    f32x4 l_run = {0.f, 0.f, 0.f, 0.f};
    f32x4 o[4];
#pragma unroll
    for (int j = 0; j < 4; ++j) o[j] = f32x4{0.f, 0.f, 0.f, 0.f};

#pragma unroll 1
    for (int kt = 0; kt <= qt; ++kt) {
      const int k0 = kt * 64;

      // S = Q K^T (log2 domain via QSCALE); K frags direct from global.
      f32x4 s[4];
#pragma unroll
      for (int j = 0; j < 4; ++j) {
        const bf16* kp = kl + (size_t)(k0 + j * 16) * 64;
        bf16x8 k0f = *(const bf16x8*)kp;
        bf16x8 k1f = *(const bf16x8*)(kp + 32);
        f32x4 z = {0.f, 0.f, 0.f, 0.f};
        z = MFMA16(qa0, k0f, z);
        z = MFMA16(qa1, k1f, z);
        s[j] = z;
      }

      if (kt == qt) {  // diagonal: causal mask
#pragma unroll
        for (int j = 0; j < 4; ++j) {
          const int kvg = k0 + j * 16 + l15;
#pragma unroll
          for (int r = 0; r < 4; ++r) {
            const int qg = q0 + wave * 16 + quad * 4 + r;
            if (kvg > qg) s[j][r] = NEG;
          }
        }
      }

      // p = exp2(s); accumulate per-lane l partials
#pragma unroll
      for (int j = 0; j < 4; ++j)
#pragma unroll
        for (int r = 0; r < 4; ++r) {
          float pv = exp2f(s[j][r]);
          s[j][r] = pv;
          l_run[r] += pv;
        }

      // P: C-layout -> per-wave LDS strip -> A-operand frags
#pragma unroll
      for (int j = 0; j < 4; ++j)
#pragma unroll
        for (int r = 0; r < 4; ++r)
          Pw[swz_off(quad * 4 + r, j * 16 + l15)] = (bf16)s[j][r];

      bf16x8 pf0 = *(const bf16x8*)(Pw + swz_off(l15, quad * 8));
      bf16x8 pf1 = *(const bf16x8*)(Pw + swz_off(l15, 32 + quad * 8));

      // PV: V^T frags direct from global.
#pragma unroll
      for (int j = 0; j < 4; ++j) {
        const bf16* vp = vl + (size_t)j * (16 * 2048) + k0;
        bf16x8 vf0 = *(const bf16x8*)vp;
        bf16x8 vf1 = *(const bf16x8*)(vp + 32);
        o[j] = MFMA16(pf0, vf0, o[j]);
        o[j] = MFMA16(pf1, vf1, o[j]);
      }
    }

    // one deferred 16-lane reduce for l (lanes of a quad hold same rows)
#pragma unroll
    for (int msk = 1; msk < 16; msk <<= 1)
#pragma unroll
      for (int r = 0; r < 4; ++r) l_run[r] += __shfl_xor(l_run[r], msk);

#pragma unroll
    for (int j = 0; j < 4; ++j) {
      const int dcol = h * 64 + j * 16 + l15;
#pragma unroll
      for (int r = 0; r < 4; ++r) {
        const int trow = q0 + wave * 16 + quad * 4 + r;
        Y[((size_t)b * 2048 + trow) * 1024 + dcol] = (bf16)(o[j][r] / l_run[r]);
      }
    }
  }
}

// ---------------------------------------------------------------------------
// Projection GEMM, bf16 async variant (plan A): out fp32 = y(bf16)*wpb^T.
// grid (8,64).
// ---------------------------------------------------------------------------
__global__ __launch_bounds__(256, 2)
void gemm_proj_a(const bf16* __restrict__ A, const bf16* __restrict__ B,
                 float* __restrict__ C) {
  __shared__ __align__(16) bf16 As[128 * 32];
  __shared__ __align__(16) bf16 Bs[128 * 32];
  const int K = 1024, N = 1024;

  const int tid  = threadIdx.x;
  const int lane = tid & 63;
  const int wave = tid >> 6;
  const int quad = lane >> 4;
  const int l15  = lane & 15;
  const int wm   = (wave >> 1) * 64;
  const int wn   = (wave & 1) * 64;
  const int m0   = blockIdx.y * 128;
  const int n0   = blockIdx.x * 128;

  f32x4 acc[4][4];
#pragma unroll
  for (int i = 0; i < 4; ++i)
#pragma unroll
    for (int j = 0; j < 4; ++j) acc[i][j] = f32x4{0.f, 0.f, 0.f, 0.f};

  const int r0 = tid >> 2;
  const int c0 = (tid & 3) * 8;
  const bf16* ag0 = A + (size_t)(m0 + r0) * K + c0;
  const bf16* ag1 = A + (size_t)(m0 + 64 + r0) * K + c0;
  const bf16* bg0 = B + (size_t)(n0 + r0) * K + c0;
  const bf16* bg1 = B + (size_t)(n0 + 64 + r0) * K + c0;
  const int lo0 = (wave * 64) * 8;
  const int lo1 = (256 + wave * 64) * 8;

  for (int k0 = 0; k0 < K; k0 += 32) {
    __syncthreads();
    async_ld16(ag0 + k0, As + lo0);
    async_ld16(ag1 + k0, As + lo1);
    async_ld16(bg0 + k0, Bs + lo0);
    async_ld16(bg1 + k0, Bs + lo1);
    __syncthreads();

    bf16x8 af[4], bfr[4];
#pragma unroll
    for (int i = 0; i < 4; ++i)
      af[i] = *(const bf16x8*)(As + (wm + i * 16 + l15) * 32 + quad * 8);
#pragma unroll
    for (int j = 0; j < 4; ++j)
      bfr[j] = *(const bf16x8*)(Bs + (wn + j * 16 + l15) * 32 + quad * 8);
#pragma unroll
    for (int i = 0; i < 4; ++i)
#pragma unroll
      for (int j = 0; j < 4; ++j)
        acc[i][j] = MFMA16(af[i], bfr[j], acc[i][j]);
  }

#pragma unroll
  for (int i = 0; i < 4; ++i) {
    const int m = m0 + wm + i * 16 + quad * 4;
#pragma unroll
    for (int j = 0; j < 4; ++j) {
      const int n = n0 + wn + j * 16 + l15;
#pragma unroll
      for (int r = 0; r < 4; ++r)
        C[(size_t)(m + r) * N + n] = acc[i][j][r];
    }
  }
}

// ---------------------------------------------------------------------------
// Projection GEMM, fp32-B fallback (plan B). grid (8,64).
// ---------------------------------------------------------------------------
__global__ __launch_bounds__(256, 2)
void gemm_proj_f(const bf16* __restrict__ A, const float* __restrict__ B,
                 float* __restrict__ C) {
  __shared__ __align__(16) bf16 As[128 * 32];
  __shared__ __align__(16) bf16 Bs[128 * 32];
  const int K = 1024, N = 1024;

  const int tid  = threadIdx.x;
  const int lane = tid & 63;
  const int wave = tid >> 6;
  const int quad = lane >> 4;
  const int l15  = lane & 15;
  const int wm   = (wave >> 1) * 64;
  const int wn   = (wave & 1) * 64;
  const int m0   = blockIdx.y * 128;
  const int n0   = blockIdx.x * 128;

  f32x4 acc[4][4];
#pragma unroll
  for (int i = 0; i < 4; ++i)
#pragma unroll
    for (int j = 0; j < 4; ++j) acc[i][j] = f32x4{0.f, 0.f, 0.f, 0.f};

  const int r0 = tid >> 2;
  const int c0 = (tid & 3) * 8;
  const size_t aoff0 = (size_t)(m0 + r0) * K + c0;
  const size_t aoff1 = (size_t)(m0 + 64 + r0) * K + c0;
  const size_t boff0 = (size_t)(n0 + r0) * K + c0;
  const size_t boff1 = (size_t)(n0 + 64 + r0) * K + c0;

  for (int k0 = 0; k0 < K; k0 += 32) {
    bf16x8 va0 = *(const bf16x8*)(A + aoff0 + k0);
    bf16x8 va1 = *(const bf16x8*)(A + aoff1 + k0);
    bf16x8 vb0 = cvt8(B + boff0 + k0);
    bf16x8 vb1 = cvt8(B + boff1 + k0);
    __syncthreads();
    *(bf16x8*)(As + tid * 8)        = va0;
    *(bf16x8*)(As + 2048 + tid * 8) = va1;
    *(bf16x8*)(Bs + tid * 8)        = vb0;
    *(bf16x8*)(Bs + 2048 + tid * 8) = vb1;
    __syncthreads();

    bf16x8 af[4], bfr[4];
#pragma unroll
    for (int i = 0; i < 4; ++i)
      af[i] = *(const bf16x8*)(As + (wm + i * 16 + l15) * 32 + quad * 8);
#pragma unroll
    for (int j = 0; j < 4; ++j)
      bfr[j] = *(const bf16x8*)(Bs + (wn + j * 16 + l15) * 32 + quad * 8);
#pragma unroll
    for (int i = 0; i < 4; ++i)
#pragma unroll
      for (int j = 0; j < 4; ++j)
        acc[i][j] = MFMA16(af[i], bfr[j], acc[i][j]);
  }

#pragma unroll
  for (int i = 0; i < 4; ++i) {
    const int m = m0 + wm + i * 16 + quad * 4;
#pragma unroll
    for (int j = 0; j < 4; ++j) {
      const int n = n0 + wn + j * 16 + l15;
#pragma unroll
      for (int r = 0; r < 4; ++r)
        C[(size_t)(m + r) * N + n] = acc[i][j][r];
    }
  }
}

// ---------------------------------------------------------------------------
extern "C" void kernel_launch(void* const* d_in, const int* in_sizes, int n_in,
                              void* d_out, int out_size, void* d_ws, size_t ws_size,
                              hipStream_t stream) {
  const float* x  = nullptr;   // 8388608 elems
  const float* wq = nullptr;   // 3145728
  const float* wp = nullptr;   // 1048576
  for (int i = 0; i < n_in; ++i) {
    if      (in_sizes[i] == 8388608) x  = (const float*)d_in[i];
    else if (in_sizes[i] == 3145728) wq = (const float*)d_in[i];
    else if (in_sizes[i] == 1048576) wp = (const float*)d_in[i];
  }
  if (!x || !wq || !wp) {
    x = (const float*)d_in[0]; wq = (const float*)d_in[1]; wp = (const float*)d_in[2];
  }

  float* out = (float*)d_out;            // [4,2048,1024] fp32, written once
  const size_t NE = (size_t)4 * 16 * 2048 * 64;  // 8388608
  bf16* kb = (bf16*)d_ws;                // base 64MB: K, V^T, Q, y
  bf16* vb = kb + NE;                    // V^T: [bh][64][2048]
  bf16* qb = vb + NE;
  bf16* yb = qb + NE;
  // extended region (bf16 copies of inputs)
  bf16* xb  = yb + NE;                   // 8388608 elems
  bf16* wqb = xb + 8388608;              // 3145728
  bf16* wpb = wqb + 3145728;             // 1048576
  const size_t need = (4 * NE + 8388608 + 3145728 + 1048576) * sizeof(bf16);
  const bool ext = ws_size >= need;      // deterministic -> graph-safe

  if (ext) {
    cvt_f32_bf16<<<(8388608 / 8 + 255) / 256, 256, 0, stream>>>(x, xb, 8388608 / 8);
    cvt_f32_bf16<<<(3145728 / 8 + 255) / 256, 256, 0, stream>>>(wq, wqb, 3145728 / 8);
    cvt_f32_bf16<<<(1048576 / 8 + 255) / 256, 256, 0, stream>>>(wp, wpb, 1048576 / 8);
    gemm_qkv_a<<<dim3(24, 64), 256, 0, stream>>>(xb, wqb, qb, kb, vb);
  } else {
    gemm_qkv_f<<<dim3(24, 64), 256, 0, stream>>>(x, wq, qb, kb, vb);
  }

  attn<<<dim3(16, 64), 256, 0, stream>>>(qb, kb, vb, yb);

  if (ext) {
    gemm_proj_a<<<dim3(8, 64), 256, 0, stream>>>(yb, wpb, out);
  } else {
    gemm_proj_f<<<dim3(8, 64), 256, 0, stream>>>(yb, wp, out);
  }
}